// Round 1
// baseline (956.898 us; speedup 1.0000x reference)
//
#include <hip/hip_runtime.h>

// ---------- types ----------
typedef __attribute__((ext_vector_type(4))) float f32x4;
typedef __attribute__((ext_vector_type(8))) __bf16 bf16x8;
typedef __attribute__((ext_vector_type(8))) unsigned short u16x8;

__device__ __forceinline__ unsigned short f2bf(float f) {
    union { float f; unsigned int u; } v; v.f = f;
    unsigned int r = v.u + 0x7FFFu + ((v.u >> 16) & 1u);   // RNE
    return (unsigned short)(r >> 16);
}
__device__ __forceinline__ float bf2f(unsigned short u) {
    union { unsigned int u; float f; } v; v.u = ((unsigned int)u) << 16; return v.f;
}

// async global->LDS, 16B per lane. LDS dest must be wave-uniform base + lane*16.
__device__ __forceinline__ void async16(const void* g, void* l) {
    __builtin_amdgcn_global_load_lds((const __attribute__((address_space(1))) void*)g,
                                     (__attribute__((address_space(3))) void*)l, 16, 0, 0);
}

// ---------- f32 -> bf16 cast (with scale) ----------
__global__ __launch_bounds__(256) void cast_bf16_kernel(const float* __restrict__ in,
                                                        unsigned short* __restrict__ out,
                                                        int n4, float scale) {
    int i = blockIdx.x * 256 + threadIdx.x;
    if (i >= n4) return;
    float4 f = ((const float4*)in)[i];
    ushort4 u;
    u.x = f2bf(f.x * scale); u.y = f2bf(f.y * scale);
    u.z = f2bf(f.z * scale); u.w = f2bf(f.w * scale);
    ((ushort4*)out)[i] = u;
}

// ---------- generic (optionally batched) GEMM: C[m,n] = sum_k A[m,k]*B[n,k] ----------
// A: bf16 rows lda, B: bf16 rows ldb (i.e. B-transposed layout), C row-major ldc.
// batch z: inner index zh = z%Hc, outer zb = z/Hc with independent strides.
// OUTMODE: 0=f32, 1=bf16.  RESMODE: 0=none, 1=f32 residual, 2=bf16 residual (same ldc, unbatched).
template <int OUTMODE, int BIAS, int RESMODE>
__global__ __launch_bounds__(256) void gemm_bt(const unsigned short* __restrict__ A,
                                               const unsigned short* __restrict__ B,
                                               void* __restrict__ C,
                                               const float* __restrict__ bias,
                                               const void* __restrict__ res,
                                               int K, int lda, int ldb, int ldc,
                                               int Hc, long sAh, long sAb, long sBh, long sBb,
                                               long sCh, long sCb) {
    __shared__ unsigned short As[128 * 32];
    __shared__ unsigned short Bs[128 * 32];
    const int t = threadIdx.x;
    const int m0 = blockIdx.y * 128, n0 = blockIdx.x * 128;
    const long z = blockIdx.z;
    const long zh = z % Hc, zb = z / Hc;
    const unsigned short* Ab = A + zh * sAh + zb * sAb + (long)m0 * lda;
    const unsigned short* Bb = B + zh * sBh + zb * sBb + (long)n0 * ldb;
    const long cbase = zh * sCh + zb * sCb;

    const int l = t & 63, w = t >> 6;
    const int lane16 = l & 15, quad = l >> 4;
    const int wm = w >> 1, wn = w & 1;
    const int aoff = (wm * 64 + lane16) * 32 + quad * 8;
    const int boff = (wn * 64 + lane16) * 32 + quad * 8;

    f32x4 acc[4][4];
#pragma unroll
    for (int i = 0; i < 4; ++i)
#pragma unroll
        for (int j = 0; j < 4; ++j) acc[i][j] = (f32x4){0.f, 0.f, 0.f, 0.f};

    for (int k0 = 0; k0 < K; k0 += 32) {
#pragma unroll
        for (int i = 0; i < 2; ++i) {
            int c = i * 256 + t;
            async16(Ab + (long)(c >> 2) * lda + k0 + (c & 3) * 8, &As[c * 8]);
        }
#pragma unroll
        for (int i = 0; i < 2; ++i) {
            int c = i * 256 + t;
            async16(Bb + (long)(c >> 2) * ldb + k0 + (c & 3) * 8, &Bs[c * 8]);
        }
        __syncthreads();
        bf16x8 af[4], bv[4];
#pragma unroll
        for (int mt = 0; mt < 4; ++mt) af[mt] = *(const bf16x8*)&As[aoff + mt * 512];
#pragma unroll
        for (int nt = 0; nt < 4; ++nt) bv[nt] = *(const bf16x8*)&Bs[boff + nt * 512];
#pragma unroll
        for (int mt = 0; mt < 4; ++mt)
#pragma unroll
            for (int nt = 0; nt < 4; ++nt)
                acc[mt][nt] = __builtin_amdgcn_mfma_f32_16x16x32_bf16(af[mt], bv[nt], acc[mt][nt], 0, 0, 0);
        __syncthreads();
    }

#pragma unroll
    for (int mt = 0; mt < 4; ++mt) {
#pragma unroll
        for (int nt = 0; nt < 4; ++nt) {
            int col = n0 + wn * 64 + nt * 16 + lane16;
            int row0 = m0 + wm * 64 + mt * 16 + quad * 4;
#pragma unroll
            for (int r = 0; r < 4; ++r) {
                long ri = (long)(row0 + r) * ldc + col;
                float v = acc[mt][nt][r];
                if (BIAS) v += bias[col];
                if (RESMODE == 1) v += ((const float*)res)[ri];
                if (RESMODE == 2) v += bf2f(((const unsigned short*)res)[ri]);
                if (OUTMODE == 1) ((unsigned short*)C)[cbase + ri] = f2bf(v);
                else              ((float*)C)[cbase + ri] = v;
            }
        }
    }
}

// ---------- transpose v part of qkv into vT[b,h,d,k] (k-major rows) ----------
__global__ __launch_bounds__(256) void transpose_v(const unsigned short* __restrict__ qkvb,
                                                   unsigned short* __restrict__ vT) {
    __shared__ unsigned short tile[64 * 72];  // +8 pad keeps 16B align, spreads banks
    const int t = threadIdx.x;
    const int k0 = blockIdx.x * 64;
    const int z = blockIdx.y;  // b*16+h
    const int b = z >> 4, h = z & 15;
    const unsigned short* src = qkvb + ((long)b * 1024 + k0) * 3072 + 2048 + h * 64;
#pragma unroll
    for (int i = 0; i < 2; ++i) {
        int idx = i * 256 + t, k = idx >> 3, c = idx & 7;
        u16x8 v = *(const u16x8*)(src + (long)k * 3072 + c * 8);
        *(u16x8*)&tile[k * 72 + c * 8] = v;
    }
    __syncthreads();
    unsigned short* dst = vT + (long)z * 65536 + k0;
#pragma unroll
    for (int i = 0; i < 2; ++i) {
        int idx = i * 256 + t, d = idx >> 3, c = idx & 7;
        u16x8 o8;
#pragma unroll
        for (int j = 0; j < 8; ++j) o8[j] = tile[(c * 8 + j) * 72 + d];
        *(u16x8*)&dst[(long)d * 1024 + c * 8] = o8;
    }
}

// ---------- head-mix + attn_prev + softmax, IN PLACE over d_out attn region ----------
// block = (q, b); reads S[b,h,q,:] for all h once, writes attn[b,g,q,:] for all g.
__global__ __launch_bounds__(256) void mix_softmax(float* __restrict__ attn,
                                                   const float* __restrict__ prev,
                                                   const float* __restrict__ Wth) {
    __shared__ float sW[256];
    __shared__ float red[4][16];
    const int t = threadIdx.x;
    const int q = blockIdx.x, b = blockIdx.y;
    sW[t] = Wth[t];
    __syncthreads();
    const long base = (long)b * 16777216 + (long)q * 1024;

    float val[4][16];
    float gmax[16];
#pragma unroll
    for (int g = 0; g < 16; ++g) gmax[g] = -1e30f;

#pragma unroll
    for (int kk = 0; kk < 4; ++kk) {
        int k = kk * 256 + t;
        float s[16];
#pragma unroll
        for (int h = 0; h < 16; ++h) s[h] = attn[base + (long)h * 1048576 + k];
#pragma unroll
        for (int g = 0; g < 16; ++g) {
            float m = prev[base + (long)g * 1048576 + k];
#pragma unroll
            for (int h = 0; h < 16; ++h) m = fmaf(sW[g * 16 + h], s[h], m);
            val[kk][g] = m;
            gmax[g] = fmaxf(gmax[g], m);
        }
    }
    const int w = t >> 6, l = t & 63;
#pragma unroll
    for (int g = 0; g < 16; ++g) {
#pragma unroll
        for (int o = 32; o >= 1; o >>= 1) gmax[g] = fmaxf(gmax[g], __shfl_xor(gmax[g], o));
    }
    if (l == 0) {
#pragma unroll
        for (int g = 0; g < 16; ++g) red[w][g] = gmax[g];
    }
    __syncthreads();
#pragma unroll
    for (int g = 0; g < 16; ++g)
        gmax[g] = fmaxf(fmaxf(red[0][g], red[1][g]), fmaxf(red[2][g], red[3][g]));
    __syncthreads();

    float gsum[16];
#pragma unroll
    for (int g = 0; g < 16; ++g) gsum[g] = 0.f;
#pragma unroll
    for (int kk = 0; kk < 4; ++kk)
#pragma unroll
        for (int g = 0; g < 16; ++g) {
            float e = __expf(val[kk][g] - gmax[g]);
            val[kk][g] = e;
            gsum[g] += e;
        }
#pragma unroll
    for (int g = 0; g < 16; ++g) {
#pragma unroll
        for (int o = 32; o >= 1; o >>= 1) gsum[g] += __shfl_xor(gsum[g], o);
    }
    if (l == 0) {
#pragma unroll
        for (int g = 0; g < 16; ++g) red[w][g] = gsum[g];
    }
    __syncthreads();
#pragma unroll
    for (int g = 0; g < 16; ++g)
        gsum[g] = 1.f / (red[0][g] + red[1][g] + red[2][g] + red[3][g]);
#pragma unroll
    for (int kk = 0; kk < 4; ++kk)
#pragma unroll
        for (int g = 0; g < 16; ++g)
            attn[base + (long)g * 1048576 + kk * 256 + t] = val[kk][g] * gsum[g];
}

// ---------- PV: o[b,q,h,:] = sum_k attn[b,h,q,k] * vT[b,h,:,k] ----------
__global__ __launch_bounds__(256) void pv_gemm(const float* __restrict__ attn,
                                               const unsigned short* __restrict__ vT,
                                               unsigned short* __restrict__ ob) {
    __shared__ unsigned short As[128 * 32];
    __shared__ unsigned short Bs[64 * 32];
    const int t = threadIdx.x;
    const int m0 = blockIdx.x * 128;
    const int z = blockIdx.y;  // b*16+h
    const int b = z >> 4, h = z & 15;
    const float* Ab = attn + (long)z * 1048576 + (long)m0 * 1024;
    const unsigned short* Bb = vT + (long)z * 65536;
    const int l = t & 63, w = t >> 6, lane16 = l & 15, quad = l >> 4;

    f32x4 acc[2][4];
#pragma unroll
    for (int i = 0; i < 2; ++i)
#pragma unroll
        for (int j = 0; j < 4; ++j) acc[i][j] = (f32x4){0.f, 0.f, 0.f, 0.f};

    for (int k0 = 0; k0 < 1024; k0 += 32) {
#pragma unroll
        for (int i = 0; i < 4; ++i) {
            int idx = i * 256 + t, row = idx >> 3, c4 = idx & 7;
            float4 f = *(const float4*)(Ab + (long)row * 1024 + k0 + c4 * 4);
            ushort4 u;
            u.x = f2bf(f.x); u.y = f2bf(f.y); u.z = f2bf(f.z); u.w = f2bf(f.w);
            *(ushort4*)&As[row * 32 + c4 * 4] = u;
        }
        {
            int c = t;  // 64 rows * 4 chunks
            async16(Bb + (long)(c >> 2) * 1024 + k0 + (c & 3) * 8, &Bs[c * 8]);
        }
        __syncthreads();
        bf16x8 af[2], bv[4];
#pragma unroll
        for (int mt = 0; mt < 2; ++mt)
            af[mt] = *(const bf16x8*)&As[(w * 32 + mt * 16 + lane16) * 32 + quad * 8];
#pragma unroll
        for (int nt = 0; nt < 4; ++nt)
            bv[nt] = *(const bf16x8*)&Bs[(nt * 16 + lane16) * 32 + quad * 8];
#pragma unroll
        for (int mt = 0; mt < 2; ++mt)
#pragma unroll
            for (int nt = 0; nt < 4; ++nt)
                acc[mt][nt] = __builtin_amdgcn_mfma_f32_16x16x32_bf16(af[mt], bv[nt], acc[mt][nt], 0, 0, 0);
        __syncthreads();
    }
#pragma unroll
    for (int mt = 0; mt < 2; ++mt)
#pragma unroll
        for (int nt = 0; nt < 4; ++nt)
#pragma unroll
            for (int r = 0; r < 4; ++r) {
                int gq = m0 + w * 32 + mt * 16 + quad * 4 + r;
                ob[((long)b * 1024 + gq) * 1024 + h * 64 + nt * 16 + lane16] = f2bf(acc[mt][nt][r]);
            }
}

// ---------- layernorm over rows of 1024 ----------
__global__ __launch_bounds__(256) void ln_kernel(const float* __restrict__ in,
                                                 const float* __restrict__ gamma,
                                                 const float* __restrict__ beta,
                                                 unsigned short* __restrict__ outb,
                                                 float* __restrict__ outf) {
    __shared__ float rs[4][2];
    const int row = blockIdx.x, t = threadIdx.x;
    const float* r = in + (long)row * 1024;
    float v[4], s = 0.f, s2 = 0.f;
#pragma unroll
    for (int i = 0; i < 4; ++i) { v[i] = r[i * 256 + t]; s += v[i]; s2 += v[i] * v[i]; }
#pragma unroll
    for (int o = 32; o >= 1; o >>= 1) { s += __shfl_xor(s, o); s2 += __shfl_xor(s2, o); }
    const int w = t >> 6, l = t & 63;
    if (l == 0) { rs[w][0] = s; rs[w][1] = s2; }
    __syncthreads();
    s = rs[0][0] + rs[1][0] + rs[2][0] + rs[3][0];
    s2 = rs[0][1] + rs[1][1] + rs[2][1] + rs[3][1];
    float mu = s * (1.f / 1024.f);
    float var = s2 * (1.f / 1024.f) - mu * mu;
    float rstd = rsqrtf(var + 1e-5f);
#pragma unroll
    for (int i = 0; i < 4; ++i) {
        int col = i * 256 + t;
        float y = (v[i] - mu) * rstd * gamma[col] + beta[col];
        if (outb) outb[(long)row * 1024 + col] = f2bf(y);
        if (outf) outf[(long)row * 1024 + col] = y;
    }
}

// ---------- GLU: out[m,j] = h[m,j] * relu(h[m,2048+j]) ----------
__global__ __launch_bounds__(256) void glu_kernel(const unsigned short* __restrict__ h,
                                                  unsigned short* __restrict__ out) {
    int i = blockIdx.x * 256 + threadIdx.x;  // chunk of 8
    int row = i >> 8, c = i & 255;
    u16x8 a8 = *(const u16x8*)(h + (long)row * 4096 + c * 8);
    u16x8 g8 = *(const u16x8*)(h + (long)row * 4096 + 2048 + c * 8);
    u16x8 o8;
#pragma unroll
    for (int j = 0; j < 8; ++j) {
        float g = bf2f(g8[j]);
        g = g > 0.f ? g : 0.f;
        o8[j] = f2bf(bf2f(a8[j]) * g);
    }
    *(u16x8*)(out + (long)row * 2048 + c * 8) = o8;
}

// ---------- launcher ----------
extern "C" void kernel_launch(void* const* d_in, const int* in_sizes, int n_in,
                              void* d_out, int out_size, void* d_ws, size_t ws_size,
                              hipStream_t stream) {
    const float* x    = (const float*)d_in[0];
    const float* prev = (const float*)d_in[1];
    const float* Wq   = (const float*)d_in[2];
    const float* Wk   = (const float*)d_in[3];
    const float* Wv   = (const float*)d_in[4];
    const float* Wth  = (const float*)d_in[5];
    const float* Wpv  = (const float*)d_in[6];
    const float* W1   = (const float*)d_in[7];
    const float* b1   = (const float*)d_in[8];
    const float* W2   = (const float*)d_in[9];
    const float* b2   = (const float*)d_in[10];
    const float* ln1g = (const float*)d_in[11];
    const float* ln1b = (const float*)d_in[12];
    const float* ln2g = (const float*)d_in[13];
    const float* ln2b = (const float*)d_in[14];

    float* out  = (float*)d_out;
    float* attn = out + 4194304;  // 64M floats, also used in-place for raw scores

    char* ws = (char*)d_ws;
    unsigned short* xb    = (unsigned short*)(ws + 0);          //  8 MB: x bf16
    unsigned short* wqkvb = (unsigned short*)(ws + 8388608);    //  6 MB: [Wq/8; Wk; Wv] bf16
    unsigned short* wpvb  = (unsigned short*)(ws + 14680064);   //  2 MB
    unsigned short* w1b   = (unsigned short*)(ws + 16777216);   //  8 MB
    unsigned short* w2b   = (unsigned short*)(ws + 25165824);   //  4 MB
    unsigned short* qkvb  = (unsigned short*)(ws + 29360128);   // 24 MB: [q k v] bf16
    unsigned short* vTb   = (unsigned short*)(ws + 54525952);   //  8 MB: v transposed
    unsigned short* obuf  = (unsigned short*)(ws + 62914560);   //  8 MB: attention out
    unsigned short* x1b   = (unsigned short*)(ws + 71303168);   //  8 MB
    unsigned short* glub  = (unsigned short*)(ws + 79691776);   // 16 MB
    unsigned short* hb    = (unsigned short*)(ws + 96468992);   // 32 MB
    float*          pre   = (float*)(ws + 130023424);           // 16 MB f32 scratch (pre-LN)
    // total 146800640 bytes

    dim3 T(256);
    // casts (Wq folded with 1/sqrt(DQK) = 1/8)
    cast_bf16_kernel<<<4096, T, 0, stream>>>(x, xb, 1048576, 1.f);
    cast_bf16_kernel<<<1024, T, 0, stream>>>(Wq, wqkvb,           262144, 0.125f);
    cast_bf16_kernel<<<1024, T, 0, stream>>>(Wk, wqkvb + 1048576, 262144, 1.f);
    cast_bf16_kernel<<<1024, T, 0, stream>>>(Wv, wqkvb + 2097152, 262144, 1.f);
    cast_bf16_kernel<<<1024, T, 0, stream>>>(Wpv, wpvb,  262144, 1.f);
    cast_bf16_kernel<<<4096, T, 0, stream>>>(W1, w1b,  1048576, 1.f);
    cast_bf16_kernel<<<2048, T, 0, stream>>>(W2, w2b,   524288, 1.f);

    // qkv = x @ [Wq;Wk;Wv]^T   (M=4096, N=3072, K=1024) -> bf16
    gemm_bt<1, 0, 0><<<dim3(24, 32, 1), T, 0, stream>>>(xb, wqkvb, qkvb, nullptr, nullptr,
        1024, 1024, 1024, 3072, 1, 0, 0, 0, 0, 0, 0);

    // vT[b,h,d,k]
    transpose_v<<<dim3(16, 64), T, 0, stream>>>(qkvb, vTb);

    // scores[b,h,q,k] = q . k  (batched over b*16+h), written into d_out attn region
    gemm_bt<0, 0, 0><<<dim3(8, 8, 64), T, 0, stream>>>(qkvb, qkvb + 1024, attn, nullptr, nullptr,
        64, 3072, 3072, 1024, 16, 64, 3145728, 64, 3145728, 1048576, 16777216);

    // head mix + prev + softmax (in place)
    mix_softmax<<<dim3(1024, 4), T, 0, stream>>>(attn, prev, Wth);

    // o = attn @ v
    pv_gemm<<<dim3(8, 64), T, 0, stream>>>(attn, vTb, obuf);

    // pre = x + o @ Wpv^T
    gemm_bt<0, 0, 1><<<dim3(8, 32, 1), T, 0, stream>>>(obuf, wpvb, pre, nullptr, x,
        1024, 1024, 1024, 1024, 1, 0, 0, 0, 0, 0, 0);

    // x1 = LN1(pre) -> bf16
    ln_kernel<<<4096, T, 0, stream>>>(pre, ln1g, ln1b, x1b, nullptr);

    // h = x1 @ W1^T + b1 -> bf16
    gemm_bt<1, 1, 0><<<dim3(32, 32, 1), T, 0, stream>>>(x1b, w1b, hb, b1, nullptr,
        1024, 1024, 1024, 4096, 1, 0, 0, 0, 0, 0, 0);

    // glu = h[:, :2048] * relu(h[:, 2048:])
    glu_kernel<<<4096, T, 0, stream>>>(hb, glub);

    // pre = glu @ W2^T + b2 + x1
    gemm_bt<0, 1, 2><<<dim3(8, 32, 1), T, 0, stream>>>(glub, w2b, pre, b2, x1b,
        2048, 2048, 2048, 1024, 1, 0, 0, 0, 0, 0, 0);

    // out = LN2(pre)
    ln_kernel<<<4096, T, 0, stream>>>(pre, ln2g, ln2b, nullptr, out);
}

// Round 2
// 947.632 us; speedup vs baseline: 1.0098x; 1.0098x over previous
//
#include <hip/hip_runtime.h>

// ---------- types ----------
typedef __attribute__((ext_vector_type(4))) float f32x4;
typedef __attribute__((ext_vector_type(8))) __bf16 bf16x8;
typedef __attribute__((ext_vector_type(8))) unsigned short u16x8;

__device__ __forceinline__ unsigned short f2bf(float f) {
    union { float f; unsigned int u; } v; v.f = f;
    unsigned int r = v.u + 0x7FFFu + ((v.u >> 16) & 1u);   // RNE
    return (unsigned short)(r >> 16);
}
__device__ __forceinline__ float bf2f(unsigned short u) {
    union { unsigned int u; float f; } v; v.u = ((unsigned int)u) << 16; return v.f;
}

// async global->LDS, 16B per lane. LDS dest must be wave-uniform base + lane*16.
__device__ __forceinline__ void async16(const void* g, void* l) {
    __builtin_amdgcn_global_load_lds((const __attribute__((address_space(1))) void*)g,
                                     (__attribute__((address_space(3))) void*)l, 16, 0, 0);
}

// ---------- merged f32 -> bf16 casts (segment per blockIdx.y) ----------
struct CastSeg { const float* src; unsigned short* dst; int n4; float scale; };
struct Cast4Args { CastSeg seg[4]; };

__global__ __launch_bounds__(256) void cast_multi(Cast4Args a) {
    CastSeg s = a.seg[blockIdx.y];
    int i = blockIdx.x * 256 + threadIdx.x;
    if (i >= s.n4) return;
    float4 f = ((const float4*)s.src)[i];
    ushort4 u;
    u.x = f2bf(f.x * s.scale); u.y = f2bf(f.y * s.scale);
    u.z = f2bf(f.z * s.scale); u.w = f2bf(f.w * s.scale);
    ((ushort4*)s.dst)[i] = u;
}

// ---------- generic (optionally batched) GEMM: C[m,n] = sum_k A[m,k]*B[n,k] ----------
template <int OUTMODE, int BIAS, int RESMODE>
__global__ __launch_bounds__(256) void gemm_bt(const unsigned short* __restrict__ A,
                                               const unsigned short* __restrict__ B,
                                               void* __restrict__ C,
                                               const float* __restrict__ bias,
                                               const void* __restrict__ res,
                                               int K, int lda, int ldb, int ldc,
                                               int Hc, long sAh, long sAb, long sBh, long sBb,
                                               long sCh, long sCb) {
    __shared__ unsigned short As[128 * 32];
    __shared__ unsigned short Bs[128 * 32];
    const int t = threadIdx.x;
    const int m0 = blockIdx.y * 128, n0 = blockIdx.x * 128;
    const long z = blockIdx.z;
    const long zh = z % Hc, zb = z / Hc;
    const unsigned short* Ab = A + zh * sAh + zb * sAb + (long)m0 * lda;
    const unsigned short* Bb = B + zh * sBh + zb * sBb + (long)n0 * ldb;
    const long cbase = zh * sCh + zb * sCb;

    const int l = t & 63, w = t >> 6;
    const int lane16 = l & 15, quad = l >> 4;
    const int wm = w >> 1, wn = w & 1;
    const int aoff = (wm * 64 + lane16) * 32 + quad * 8;
    const int boff = (wn * 64 + lane16) * 32 + quad * 8;

    f32x4 acc[4][4];
#pragma unroll
    for (int i = 0; i < 4; ++i)
#pragma unroll
        for (int j = 0; j < 4; ++j) acc[i][j] = (f32x4){0.f, 0.f, 0.f, 0.f};

    for (int k0 = 0; k0 < K; k0 += 32) {
#pragma unroll
        for (int i = 0; i < 2; ++i) {
            int c = i * 256 + t;
            async16(Ab + (long)(c >> 2) * lda + k0 + (c & 3) * 8, &As[c * 8]);
        }
#pragma unroll
        for (int i = 0; i < 2; ++i) {
            int c = i * 256 + t;
            async16(Bb + (long)(c >> 2) * ldb + k0 + (c & 3) * 8, &Bs[c * 8]);
        }
        __syncthreads();
        bf16x8 af[4], bv[4];
#pragma unroll
        for (int mt = 0; mt < 4; ++mt) af[mt] = *(const bf16x8*)&As[aoff + mt * 512];
#pragma unroll
        for (int nt = 0; nt < 4; ++nt) bv[nt] = *(const bf16x8*)&Bs[boff + nt * 512];
#pragma unroll
        for (int mt = 0; mt < 4; ++mt)
#pragma unroll
            for (int nt = 0; nt < 4; ++nt)
                acc[mt][nt] = __builtin_amdgcn_mfma_f32_16x16x32_bf16(af[mt], bv[nt], acc[mt][nt], 0, 0, 0);
        __syncthreads();
    }

#pragma unroll
    for (int mt = 0; mt < 4; ++mt) {
#pragma unroll
        for (int nt = 0; nt < 4; ++nt) {
            int col = n0 + wn * 64 + nt * 16 + lane16;
            int row0 = m0 + wm * 64 + mt * 16 + quad * 4;
#pragma unroll
            for (int r = 0; r < 4; ++r) {
                long ri = (long)(row0 + r) * ldc + col;
                float v = acc[mt][nt][r];
                if (BIAS) v += bias[col];
                if (RESMODE == 1) v += ((const float*)res)[ri];
                if (RESMODE == 2) v += bf2f(((const unsigned short*)res)[ri]);
                if (OUTMODE == 1) ((unsigned short*)C)[cbase + ri] = f2bf(v);
                else              ((float*)C)[cbase + ri] = v;
            }
        }
    }
}

// ---------- transpose v part of qkv into vT[b,h,d,k] (k-major rows) ----------
__global__ __launch_bounds__(256) void transpose_v(const unsigned short* __restrict__ qkvb,
                                                   unsigned short* __restrict__ vT) {
    __shared__ unsigned short tile[64 * 72];
    const int t = threadIdx.x;
    const int k0 = blockIdx.x * 64;
    const int z = blockIdx.y;  // b*16+h
    const int b = z >> 4, h = z & 15;
    const unsigned short* src = qkvb + ((long)b * 1024 + k0) * 3072 + 2048 + h * 64;
#pragma unroll
    for (int i = 0; i < 2; ++i) {
        int idx = i * 256 + t, k = idx >> 3, c = idx & 7;
        u16x8 v = *(const u16x8*)(src + (long)k * 3072 + c * 8);
        *(u16x8*)&tile[k * 72 + c * 8] = v;
    }
    __syncthreads();
    unsigned short* dst = vT + (long)z * 65536 + k0;
#pragma unroll
    for (int i = 0; i < 2; ++i) {
        int idx = i * 256 + t, d = idx >> 3, c = idx & 7;
        u16x8 o8;
#pragma unroll
        for (int j = 0; j < 8; ++j) o8[j] = tile[(c * 8 + j) * 72 + d];
        *(u16x8*)&dst[(long)d * 1024 + c * 8] = o8;
    }
}

// ---------- head-mix + attn_prev + softmax ----------
// In-place f32 over d_out attn region + bf16 copy to ab. Each thread owns 4
// consecutive k (float4/ushort4 vector access throughout).
__global__ __launch_bounds__(256) void mix_softmax(float* __restrict__ attn,
                                                   unsigned short* __restrict__ ab,
                                                   const float* __restrict__ prev,
                                                   const float* __restrict__ Wth) {
    __shared__ float sW[256];
    __shared__ float red[4][16];
    const int t = threadIdx.x;
    const int q = blockIdx.x, b = blockIdx.y;
    sW[t] = Wth[t];
    __syncthreads();
    const long base = (long)b * 16777216 + (long)q * 1024 + t * 4;

    float4 val[16];
#pragma unroll
    for (int g = 0; g < 16; ++g) val[g] = *(const float4*)(prev + base + (long)g * 1048576);
#pragma unroll
    for (int h = 0; h < 16; ++h) {
        float4 s4 = *(const float4*)(attn + base + (long)h * 1048576);
#pragma unroll
        for (int g = 0; g < 16; ++g) {
            float wg = sW[g * 16 + h];
            val[g].x = fmaf(wg, s4.x, val[g].x);
            val[g].y = fmaf(wg, s4.y, val[g].y);
            val[g].z = fmaf(wg, s4.z, val[g].z);
            val[g].w = fmaf(wg, s4.w, val[g].w);
        }
    }
    const int w = t >> 6, l = t & 63;
    float gm[16];
#pragma unroll
    for (int g = 0; g < 16; ++g) {
        float m = fmaxf(fmaxf(val[g].x, val[g].y), fmaxf(val[g].z, val[g].w));
#pragma unroll
        for (int o = 32; o >= 1; o >>= 1) m = fmaxf(m, __shfl_xor(m, o));
        gm[g] = m;
    }
    if (l == 0) {
#pragma unroll
        for (int g = 0; g < 16; ++g) red[w][g] = gm[g];
    }
    __syncthreads();
#pragma unroll
    for (int g = 0; g < 16; ++g)
        gm[g] = fmaxf(fmaxf(red[0][g], red[1][g]), fmaxf(red[2][g], red[3][g]));
    __syncthreads();

    float gs[16];
#pragma unroll
    for (int g = 0; g < 16; ++g) {
        val[g].x = __expf(val[g].x - gm[g]);
        val[g].y = __expf(val[g].y - gm[g]);
        val[g].z = __expf(val[g].z - gm[g]);
        val[g].w = __expf(val[g].w - gm[g]);
        float s = (val[g].x + val[g].y) + (val[g].z + val[g].w);
#pragma unroll
        for (int o = 32; o >= 1; o >>= 1) s += __shfl_xor(s, o);
        gs[g] = s;
    }
    if (l == 0) {
#pragma unroll
        for (int g = 0; g < 16; ++g) red[w][g] = gs[g];
    }
    __syncthreads();
#pragma unroll
    for (int g = 0; g < 16; ++g) {
        float inv = 1.f / (red[0][g] + red[1][g] + red[2][g] + red[3][g]);
        float4 r;
        r.x = val[g].x * inv; r.y = val[g].y * inv;
        r.z = val[g].z * inv; r.w = val[g].w * inv;
        *(float4*)(attn + base + (long)g * 1048576) = r;
        ushort4 u;
        u.x = f2bf(r.x); u.y = f2bf(r.y); u.z = f2bf(r.z); u.w = f2bf(r.w);
        *(ushort4*)(ab + base + (long)g * 1048576) = u;
    }
}

// ---------- PV: o[b,q,h,:] = sum_k ab[b,h,q,k] * vT[b,h,:,k]  (all bf16, async staging) ----------
__global__ __launch_bounds__(256) void pv_gemm(const unsigned short* __restrict__ ab,
                                               const unsigned short* __restrict__ vT,
                                               unsigned short* __restrict__ ob) {
    __shared__ unsigned short As[128 * 32];
    __shared__ unsigned short Bs[64 * 32];
    const int t = threadIdx.x;
    const int m0 = blockIdx.x * 128;
    const int z = blockIdx.y;  // b*16+h
    const int b = z >> 4, h = z & 15;
    const unsigned short* Ab = ab + (long)z * 1048576 + (long)m0 * 1024;
    const unsigned short* Bb = vT + (long)z * 65536;
    const int l = t & 63, w = t >> 6, lane16 = l & 15, quad = l >> 4;

    f32x4 acc[2][4];
#pragma unroll
    for (int i = 0; i < 2; ++i)
#pragma unroll
        for (int j = 0; j < 4; ++j) acc[i][j] = (f32x4){0.f, 0.f, 0.f, 0.f};

    for (int k0 = 0; k0 < 1024; k0 += 32) {
#pragma unroll
        for (int i = 0; i < 2; ++i) {
            int c = i * 256 + t;
            async16(Ab + (long)(c >> 2) * 1024 + k0 + (c & 3) * 8, &As[c * 8]);
        }
        {
            int c = t;
            async16(Bb + (long)(c >> 2) * 1024 + k0 + (c & 3) * 8, &Bs[c * 8]);
        }
        __syncthreads();
        bf16x8 af[2], bv[4];
#pragma unroll
        for (int mt = 0; mt < 2; ++mt)
            af[mt] = *(const bf16x8*)&As[(w * 32 + mt * 16 + lane16) * 32 + quad * 8];
#pragma unroll
        for (int nt = 0; nt < 4; ++nt)
            bv[nt] = *(const bf16x8*)&Bs[(nt * 16 + lane16) * 32 + quad * 8];
#pragma unroll
        for (int mt = 0; mt < 2; ++mt)
#pragma unroll
            for (int nt = 0; nt < 4; ++nt)
                acc[mt][nt] = __builtin_amdgcn_mfma_f32_16x16x32_bf16(af[mt], bv[nt], acc[mt][nt], 0, 0, 0);
        __syncthreads();
    }
#pragma unroll
    for (int mt = 0; mt < 2; ++mt)
#pragma unroll
        for (int nt = 0; nt < 4; ++nt)
#pragma unroll
            for (int r = 0; r < 4; ++r) {
                int gq = m0 + w * 32 + mt * 16 + quad * 4 + r;
                ob[((long)b * 1024 + gq) * 1024 + h * 64 + nt * 16 + lane16] = f2bf(acc[mt][nt][r]);
            }
}

// ---------- layernorm over rows of 1024 ----------
__global__ __launch_bounds__(256) void ln_kernel(const float* __restrict__ in,
                                                 const float* __restrict__ gamma,
                                                 const float* __restrict__ beta,
                                                 unsigned short* __restrict__ outb,
                                                 float* __restrict__ outf) {
    __shared__ float rs[4][2];
    const int row = blockIdx.x, t = threadIdx.x;
    const float* r = in + (long)row * 1024;
    float v[4], s = 0.f, s2 = 0.f;
#pragma unroll
    for (int i = 0; i < 4; ++i) { v[i] = r[i * 256 + t]; s += v[i]; s2 += v[i] * v[i]; }
#pragma unroll
    for (int o = 32; o >= 1; o >>= 1) { s += __shfl_xor(s, o); s2 += __shfl_xor(s2, o); }
    const int w = t >> 6, l = t & 63;
    if (l == 0) { rs[w][0] = s; rs[w][1] = s2; }
    __syncthreads();
    s = rs[0][0] + rs[1][0] + rs[2][0] + rs[3][0];
    s2 = rs[0][1] + rs[1][1] + rs[2][1] + rs[3][1];
    float mu = s * (1.f / 1024.f);
    float var = s2 * (1.f / 1024.f) - mu * mu;
    float rstd = rsqrtf(var + 1e-5f);
#pragma unroll
    for (int i = 0; i < 4; ++i) {
        int col = i * 256 + t;
        float y = (v[i] - mu) * rstd * gamma[col] + beta[col];
        if (outb) outb[(long)row * 1024 + col] = f2bf(y);
        if (outf) outf[(long)row * 1024 + col] = y;
    }
}

// ---------- GLU: out[m,j] = h[m,j] * relu(h[m,2048+j]) ----------
__global__ __launch_bounds__(256) void glu_kernel(const unsigned short* __restrict__ h,
                                                  unsigned short* __restrict__ out) {
    int i = blockIdx.x * 256 + threadIdx.x;  // chunk of 8
    int row = i >> 8, c = i & 255;
    u16x8 a8 = *(const u16x8*)(h + (long)row * 4096 + c * 8);
    u16x8 g8 = *(const u16x8*)(h + (long)row * 4096 + 2048 + c * 8);
    u16x8 o8;
#pragma unroll
    for (int j = 0; j < 8; ++j) {
        float g = bf2f(g8[j]);
        g = g > 0.f ? g : 0.f;
        o8[j] = f2bf(bf2f(a8[j]) * g);
    }
    *(u16x8*)(out + (long)row * 2048 + c * 8) = o8;
}

// ---------- launcher ----------
extern "C" void kernel_launch(void* const* d_in, const int* in_sizes, int n_in,
                              void* d_out, int out_size, void* d_ws, size_t ws_size,
                              hipStream_t stream) {
    const float* x    = (const float*)d_in[0];
    const float* prev = (const float*)d_in[1];
    const float* Wq   = (const float*)d_in[2];
    const float* Wk   = (const float*)d_in[3];
    const float* Wv   = (const float*)d_in[4];
    const float* Wth  = (const float*)d_in[5];
    const float* Wpv  = (const float*)d_in[6];
    const float* W1   = (const float*)d_in[7];
    const float* b1   = (const float*)d_in[8];
    const float* W2   = (const float*)d_in[9];
    const float* b2   = (const float*)d_in[10];
    const float* ln1g = (const float*)d_in[11];
    const float* ln1b = (const float*)d_in[12];
    const float* ln2g = (const float*)d_in[13];
    const float* ln2b = (const float*)d_in[14];

    float* out  = (float*)d_out;
    float* attn = out + 4194304;  // attn region: scores f32 in-place -> softmaxed attn

    // d_out `out` region (16 MiB) doubles as scratch until the final LN2:
    unsigned short* vTb  = (unsigned short*)d_out;                    // 8 MiB  [transpose_v .. pv]
    unsigned short* obuf = (unsigned short*)((char*)d_out + 8388608); // 8 MiB  [pv .. wpv gemm]

    // ws layout (MiB). Phase 1 (pre-attention): qkvb 0-24, xb 24-32, wqkvb 32-38.
    // Phase 2 (attention): ab 0-128 (overlays phase-1 buffers, all dead by then).
    // Phase 3 (post-pv): wpvb 0-2, w1b 2-10, w2b 10-14, pre 14-30, x1b 30-38,
    //                    hb 38-70, glub 70-86. Peak 128 MiB <= proven 140 MiB.
    char* ws = (char*)d_ws;
    unsigned short* qkvb  = (unsigned short*)(ws + 0);
    unsigned short* xb    = (unsigned short*)(ws + 25165824);
    unsigned short* wqkvb = (unsigned short*)(ws + 33554432);
    unsigned short* ab    = (unsigned short*)(ws + 0);
    unsigned short* wpvb  = (unsigned short*)(ws + 0);
    unsigned short* w1b   = (unsigned short*)(ws + 2097152);
    unsigned short* w2b   = (unsigned short*)(ws + 10485760);
    float*          pre   = (float*)(ws + 14680064);
    unsigned short* x1b   = (unsigned short*)(ws + 31457280);
    unsigned short* hb    = (unsigned short*)(ws + 39845888);
    unsigned short* glub  = (unsigned short*)(ws + 73400320);

    dim3 T(256);

    // casts for x + qkv weights (Wq folded with 1/8)
    Cast4Args c1;
    c1.seg[0] = { x,  xb,              1048576, 1.f };
    c1.seg[1] = { Wq, wqkvb,           262144, 0.125f };
    c1.seg[2] = { Wk, wqkvb + 1048576, 262144, 1.f };
    c1.seg[3] = { Wv, wqkvb + 2097152, 262144, 1.f };
    cast_multi<<<dim3(4096, 4), T, 0, stream>>>(c1);

    // qkv = x @ [Wq;Wk;Wv]^T   (M=4096, N=3072, K=1024) -> bf16 interleaved
    gemm_bt<1, 0, 0><<<dim3(24, 32, 1), T, 0, stream>>>(xb, wqkvb, qkvb, nullptr, nullptr,
        1024, 1024, 1024, 3072, 1, 0, 0, 0, 0, 0, 0);

    // vT[b,h,d,k] into d_out scratch
    transpose_v<<<dim3(16, 64), T, 0, stream>>>(qkvb, vTb);

    // scores[b,h,q,k] f32 into d_out attn region
    gemm_bt<0, 0, 0><<<dim3(8, 8, 64), T, 0, stream>>>(qkvb, qkvb + 1024, attn, nullptr, nullptr,
        64, 3072, 3072, 1024, 16, 64, 3145728, 64, 3145728, 1048576, 16777216);

    // head mix + prev + softmax: f32 in place + bf16 copy to ab
    mix_softmax<<<dim3(1024, 4), T, 0, stream>>>(attn, ab, prev, Wth);

    // o = attn @ v  (bf16 in, bf16 out to d_out scratch)
    pv_gemm<<<dim3(8, 64), T, 0, stream>>>(ab, vTb, obuf);

    // casts for post-attention weights (overlay ab; launched after pv)
    Cast4Args c2;
    c2.seg[0] = { Wpv, wpvb, 262144, 1.f };
    c2.seg[1] = { W1,  w1b, 1048576, 1.f };
    c2.seg[2] = { W2,  w2b,  524288, 1.f };
    c2.seg[3] = { Wpv, wpvb, 0, 1.f };   // unused
    cast_multi<<<dim3(4096, 3), T, 0, stream>>>(c2);

    // pre = x + o @ Wpv^T
    gemm_bt<0, 0, 1><<<dim3(8, 32, 1), T, 0, stream>>>(obuf, wpvb, pre, nullptr, x,
        1024, 1024, 1024, 1024, 1, 0, 0, 0, 0, 0, 0);

    // x1 = LN1(pre) -> bf16
    ln_kernel<<<4096, T, 0, stream>>>(pre, ln1g, ln1b, x1b, nullptr);

    // h = x1 @ W1^T + b1 -> bf16
    gemm_bt<1, 1, 0><<<dim3(32, 32, 1), T, 0, stream>>>(x1b, w1b, hb, b1, nullptr,
        1024, 1024, 1024, 4096, 1, 0, 0, 0, 0, 0, 0);

    // glu = h[:, :2048] * relu(h[:, 2048:])
    glu_kernel<<<4096, T, 0, stream>>>(hb, glub);

    // pre = glu @ W2^T + b2 + x1
    gemm_bt<0, 1, 2><<<dim3(8, 32, 1), T, 0, stream>>>(glub, w2b, pre, b2, x1b,
        2048, 2048, 2048, 1024, 1, 0, 0, 0, 0, 0, 0);

    // out = LN2(pre)
    ln_kernel<<<4096, T, 0, stream>>>(pre, ln2g, ln2b, nullptr, out);
}